// Round 1
// baseline (669.181 us; speedup 1.0000x reference)
//
#include <hip/hip_runtime.h>

#define D 128
#define DV2 64   // D/2 float2 per row

// ---------- Phase 1: histogram of destination rows ----------
__global__ void k_hist(const int* __restrict__ rows, int E, int* __restrict__ counts) {
    int i = blockIdx.x * blockDim.x + threadIdx.x;
    if (i < E) atomicAdd(&counts[rows[i]], 1);
}

// ---------- Phase 2: exclusive scan over counts (3-pass) ----------
__global__ void k_scanA(const int* __restrict__ counts, int N,
                        int* __restrict__ offsets, int* __restrict__ blockSums) {
    __shared__ int s[256];
    int i = blockIdx.x * 256 + threadIdx.x;
    int v = (i < N) ? counts[i] : 0;
    s[threadIdx.x] = v;
    __syncthreads();
    for (int off = 1; off < 256; off <<= 1) {
        int t = (threadIdx.x >= (unsigned)off) ? s[threadIdx.x - off] : 0;
        __syncthreads();
        s[threadIdx.x] += t;
        __syncthreads();
    }
    if (i < N) offsets[i] = s[threadIdx.x] - v;          // exclusive within block
    if (threadIdx.x == 255) blockSums[blockIdx.x] = s[255];
}

__global__ void k_scanB(int* __restrict__ blockSums, int nb) {
    __shared__ int s[1024];
    int v = ((int)threadIdx.x < nb) ? blockSums[threadIdx.x] : 0;
    s[threadIdx.x] = v;
    __syncthreads();
    for (int off = 1; off < 1024; off <<= 1) {
        int t = (threadIdx.x >= (unsigned)off) ? s[threadIdx.x - off] : 0;
        __syncthreads();
        s[threadIdx.x] += t;
        __syncthreads();
    }
    if ((int)threadIdx.x < nb) blockSums[threadIdx.x] = s[threadIdx.x] - v;  // exclusive
}

__global__ void k_scanC(int* __restrict__ offsets, int* __restrict__ cursor,
                        const int* __restrict__ blockSums, int N, int E) {
    int i = blockIdx.x * 256 + threadIdx.x;
    if (i < N) {
        int o = offsets[i] + blockSums[blockIdx.x];
        offsets[i] = o;
        cursor[i] = o;
    }
    if (i == 0) offsets[N] = E;
}

// ---------- Phase 3: scatter (col, val) pairs into CSR order ----------
__global__ void k_scatter(const int* __restrict__ rows, const int* __restrict__ cols,
                          const float* __restrict__ vals, int E,
                          int* __restrict__ cursor, int2* __restrict__ sorted) {
    int i = blockIdx.x * blockDim.x + threadIdx.x;
    if (i < E) {
        int r = rows[i];
        int pos = atomicAdd(&cursor[r], 1);
        sorted[pos] = make_int2(cols[i], __float_as_int(vals[i]));
    }
}

// ---------- Phase 4: one wave per destination row, accumulate in registers ----------
__global__ void k_accum(const int2* __restrict__ sorted, const int* __restrict__ offsets,
                        const float2* __restrict__ emb, float2* __restrict__ out, int N) {
    int gw   = (blockIdx.x * blockDim.x + threadIdx.x) >> 6;  // row id
    int lane = threadIdx.x & 63;
    if (gw >= N) return;
    int beg = offsets[gw];
    int end = offsets[gw + 1];
    float2 acc = make_float2(0.f, 0.f);
    for (int base = beg; base < end; base += 64) {
        int cnt = min(64, end - base);
        int c = 0, vb = 0;
        if (lane < cnt) {
            int2 cv = sorted[base + lane];   // coalesced 8B/lane
            c = cv.x; vb = cv.y;
        }
        for (int j = 0; j < cnt; ++j) {
            int   cj = __shfl(c, j);
            float vj = __int_as_float(__shfl(vb, j));
            float2 e = emb[(size_t)cj * DV2 + lane];  // coalesced 512B/wave gather
            acc.x += vj * e.x;
            acc.y += vj * e.y;
        }
    }
    out[(size_t)gw * DV2 + lane] = acc;
}

// ---------- Fallback: direct atomic scatter-add (if ws too small) ----------
__global__ void k_atomic(const int* __restrict__ rows, const int* __restrict__ cols,
                         const float* __restrict__ vals, const float2* __restrict__ emb,
                         float* __restrict__ out, int E) {
    long long g = (long long)blockIdx.x * blockDim.x + threadIdx.x;
    int e    = (int)(g >> 6);
    int lane = (int)(g & 63);
    if (e >= E) return;
    int r = rows[e], c = cols[e];
    float v = vals[e];
    float2 em = emb[(size_t)c * DV2 + lane];
    atomicAdd(&out[(size_t)r * D + lane * 2    ], v * em.x);
    atomicAdd(&out[(size_t)r * D + lane * 2 + 1], v * em.y);
}

extern "C" void kernel_launch(void* const* d_in, const int* in_sizes, int n_in,
                              void* d_out, int out_size, void* d_ws, size_t ws_size,
                              hipStream_t stream) {
    const int*   adj  = (const int*)d_in[0];     // [2, E] int32
    const float* vals = (const float*)d_in[1];   // [E] f32
    const float* emb  = (const float*)d_in[2];   // [N, 128] f32
    int E = in_sizes[1];
    int N = in_sizes[2] / D;
    const int* rows = adj;
    const int* cols = adj + E;
    float* out = (float*)d_out;

    int nbA = (N + 255) / 256;

    // workspace layout
    size_t off_sorted  = 0;
    size_t sz_sorted   = (size_t)E * 8;
    size_t off_offsets = (off_sorted + sz_sorted + 15) & ~(size_t)15;
    size_t sz_offsets  = (size_t)(N + 1) * 4;
    size_t off_cursor  = (off_offsets + sz_offsets + 15) & ~(size_t)15;
    size_t sz_cursor   = (size_t)N * 4;
    size_t off_bs      = (off_cursor + sz_cursor + 15) & ~(size_t)15;
    size_t sz_bs       = (size_t)nbA * 4;
    size_t need        = off_bs + sz_bs;

    if (ws_size >= need && nbA <= 1024) {
        char* ws = (char*)d_ws;
        int2* sorted    = (int2*)(ws + off_sorted);
        int*  offsets   = (int*) (ws + off_offsets);
        int*  cursor    = (int*) (ws + off_cursor);   // doubles as counts, then cursor
        int*  blockSums = (int*) (ws + off_bs);

        hipMemsetAsync(cursor, 0, sz_cursor, stream);
        k_hist   <<<(E + 255) / 256, 256, 0, stream>>>(rows, E, cursor);
        k_scanA  <<<nbA, 256, 0, stream>>>(cursor, N, offsets, blockSums);
        k_scanB  <<<1, 1024, 0, stream>>>(blockSums, nbA);
        k_scanC  <<<nbA, 256, 0, stream>>>(offsets, cursor, blockSums, N, E);
        k_scatter<<<(E + 255) / 256, 256, 0, stream>>>(rows, cols, vals, E, cursor, sorted);

        int blocks = (int)(((long long)N * 64 + 255) / 256);
        k_accum  <<<blocks, 256, 0, stream>>>(sorted, offsets, (const float2*)emb,
                                              (float2*)out, N);
    } else {
        hipMemsetAsync(out, 0, (size_t)out_size * sizeof(float), stream);
        long long tot = (long long)E * 64;
        int blocks = (int)((tot + 255) / 256);
        k_atomic<<<blocks, 256, 0, stream>>>(rows, cols, vals, (const float2*)emb, out, E);
    }
}